// Round 3
// baseline (111.472 us; speedup 1.0000x reference)
//
#include <hip/hip_runtime.h>

#define B_SZ 16
#define T_SZ 512
#define D_SZ 384
#define MAX_DUR 8
#define OUT_LEN (T_SZ * (MAX_DUR - 1))   // 3584
#define D4 96                            // floats4 per row
#define TILE 64                          // output rows per block
#define NTILE (OUT_LEN / TILE)           // 56
#define NTHREADS 256

// Fused: per-block recompute of the batch csum (cheap: 512 ints), then
// 64 binary searches for this block's row-tile, then 24 coalesced float4
// writes per thread. Grid (NTILE, B_SZ).
__global__ void __launch_bounds__(NTHREADS) lenreg_fused_kernel(
    const float4* __restrict__ xs,   // [B, T, 96] float4
    const int*    __restrict__ ds,   // [B, T]
    const int*    __restrict__ ilens,// [B]
    float4*       __restrict__ out)  // [B, OUT_LEN, 96] float4
{
    __shared__ int s_csum[T_SZ];
    __shared__ int s_wave[4];
    __shared__ int s_idx[TILE];      // -1 = pad row

    const int t    = threadIdx.x;
    const int tile = blockIdx.x;
    const int b    = blockIdx.y;
    const int lane = t & 63;
    const int w    = t >> 6;         // wave id 0..3

    const int ilen = ilens[b];

    // ---- masked load of ds row: 2 consecutive ints per thread (int2) ----
    const int2 dv = ((const int2*)(ds + b * T_SZ))[t];
    const int i0 = 2 * t, i1 = 2 * t + 1;
    int v0 = (i0 < ilen) ? dv.x : 0;
    int v1 = (i1 < ilen) ? dv.y : 0;

    // ---- two-level inclusive scan of 512 elements ----
    int x = v0 + v1;                 // pair sum
    #pragma unroll
    for (int off = 1; off < 64; off <<= 1) {
        int y = __shfl_up(x, off, 64);
        if (lane >= off) x += y;
    }
    if (lane == 63) s_wave[w] = x;   // per-wave total (128 elements each)
    __syncthreads();
    int base = 0;
    #pragma unroll
    for (int i = 0; i < 3; ++i)
        if (i < w) base += s_wave[i];
    const int c1 = base + x;         // inclusive csum at element i1
    s_csum[i1] = c1;
    s_csum[i0] = c1 - v1;
    __syncthreads();

    const int total = s_csum[T_SZ - 1];

    // ---- 64 searches for this tile's output rows ----
    if (t < TILE) {
        const int k = tile * TILE + t;
        int lo = 0, hi = T_SZ;       // first index with csum > k (0..512)
        while (lo < hi) {
            int mid = (lo + hi) >> 1;
            if (s_csum[mid] <= k) lo = mid + 1; else hi = mid;
        }
        int idx = lo < (T_SZ - 1) ? lo : (T_SZ - 1);
        s_idx[t] = (k < total) ? idx : -1;
    }
    __syncthreads();

    // ---- streaming gather: TILE*96 = 6144 float4 per block, 24/thread ----
    const float4* xsrow  = xs  + (size_t)b * T_SZ * D4;
    float4*       outrow = out + ((size_t)b * OUT_LEN + (size_t)tile * TILE) * D4;
    #pragma unroll
    for (int j = t; j < TILE * D4; j += NTHREADS) {
        const int r  = j / D4;       // magic-mul
        const int d4 = j - r * D4;
        const int i  = s_idx[r];
        float4 v = {0.f, 0.f, 0.f, 0.f};
        if (i >= 0) v = xsrow[i * D4 + d4];
        outrow[j] = v;
    }
}

extern "C" void kernel_launch(void* const* d_in, const int* in_sizes, int n_in,
                              void* d_out, int out_size, void* d_ws, size_t ws_size,
                              hipStream_t stream) {
    const float* xs    = (const float*)d_in[0];
    const int*   ds    = (const int*)d_in[1];
    const int*   ilens = (const int*)d_in[2];
    float*       out   = (float*)d_out;

    dim3 grid(NTILE, B_SZ);          // 56 x 16 = 896 blocks
    lenreg_fused_kernel<<<grid, NTHREADS, 0, stream>>>(
        (const float4*)xs, ds, ilens, (float4*)out);
}

// Round 5
// 110.900 us; speedup vs baseline: 1.0052x; 1.0052x over previous
//
#include <hip/hip_runtime.h>

#define B_SZ 16
#define T_SZ 512
#define D_SZ 384
#define MAX_DUR 8
#define OUT_LEN (T_SZ * (MAX_DUR - 1))   // 3584
#define D4 96                            // float4 per row
#define TILE 32                          // output rows per block
#define NTILE (OUT_LEN / TILE)           // 112
#define NTHREADS 256
#define ITERS ((TILE * D4) / NTHREADS)   // 12

// clang-native 16B vector (HIP's float4 is a class; the nontemporal builtin
// requires a native vector type). Same layout / same dwordx4 instruction.
typedef float vfloat4 __attribute__((ext_vector_type(4)));

// Fused: per-block recompute of the batch csum (512 ints, ~0.2us), 32 binary
// searches for this block's row tile, then 12 nontemporal float4 stores per
// thread. Grid (112, 16) = 1792 blocks = exactly 7 blocks/CU (no tail).
__global__ void __launch_bounds__(NTHREADS) lenreg_fused_kernel(
    const vfloat4* __restrict__ xs,   // [B, T, 96] float4
    const int*     __restrict__ ds,   // [B, T]
    const int*     __restrict__ ilens,// [B]
    vfloat4*       __restrict__ out)  // [B, OUT_LEN, 96] float4
{
    __shared__ int s_csum[T_SZ];
    __shared__ int s_wave[4];
    __shared__ int s_idx[TILE];      // -1 = pad row

    const int t    = threadIdx.x;
    const int tile = blockIdx.x;
    const int b    = blockIdx.y;
    const int lane = t & 63;
    const int w    = t >> 6;         // wave id 0..3

    const int ilen = ilens[b];

    // ---- masked load of ds row: 2 consecutive ints per thread ----
    const int2 dv = ((const int2*)(ds + b * T_SZ))[t];
    const int i0 = 2 * t, i1 = 2 * t + 1;
    int v0 = (i0 < ilen) ? dv.x : 0;
    int v1 = (i1 < ilen) ? dv.y : 0;

    // ---- two-level inclusive scan of 512 elements ----
    int x = v0 + v1;                 // pair sum
    #pragma unroll
    for (int off = 1; off < 64; off <<= 1) {
        int y = __shfl_up(x, off, 64);
        if (lane >= off) x += y;
    }
    if (lane == 63) s_wave[w] = x;   // per-wave total (128 elements each)
    __syncthreads();
    int base = 0;
    #pragma unroll
    for (int i = 0; i < 3; ++i)
        if (i < w) base += s_wave[i];
    const int c1 = base + x;         // inclusive csum at element i1
    s_csum[i1] = c1;
    s_csum[i0] = c1 - v1;
    __syncthreads();

    const int total = s_csum[T_SZ - 1];

    // ---- 32 searches for this tile's output rows ----
    if (t < TILE) {
        const int k = tile * TILE + t;
        int lo = 0, hi = T_SZ;       // first index with csum > k (result 0..512)
        while (lo < hi) {
            int mid = (lo + hi) >> 1;
            if (s_csum[mid] <= k) lo = mid + 1; else hi = mid;
        }
        int idx = lo < (T_SZ - 1) ? lo : (T_SZ - 1);
        s_idx[t] = (k < total) ? idx : -1;
    }
    __syncthreads();

    // ---- streaming gather: TILE*96 = 3072 float4/block, 12/thread, fully
    // unrolled for ILP; nontemporal stores keep xs L2-resident ----
    const vfloat4* xsrow  = xs  + (size_t)b * T_SZ * D4;
    vfloat4*       outrow = out + ((size_t)b * OUT_LEN + (size_t)tile * TILE) * D4;
    #pragma unroll
    for (int k = 0; k < ITERS; ++k) {
        const int j  = t + k * NTHREADS;
        const int r  = j / D4;       // magic-mul
        const int d4 = j - r * D4;
        const int i  = s_idx[r];
        vfloat4 v = {0.f, 0.f, 0.f, 0.f};
        if (i >= 0) v = xsrow[i * D4 + d4];
        __builtin_nontemporal_store(v, &outrow[j]);
    }
}

extern "C" void kernel_launch(void* const* d_in, const int* in_sizes, int n_in,
                              void* d_out, int out_size, void* d_ws, size_t ws_size,
                              hipStream_t stream) {
    const float* xs    = (const float*)d_in[0];
    const int*   ds    = (const int*)d_in[1];
    const int*   ilens = (const int*)d_in[2];
    float*       out   = (float*)d_out;

    dim3 grid(NTILE, B_SZ);          // 112 x 16 = 1792 blocks = 7/CU exact
    lenreg_fused_kernel<<<grid, NTHREADS, 0, stream>>>(
        (const vfloat4*)xs, ds, ilens, (vfloat4*)out);
}